// Round 5
// baseline (4252.058 us; speedup 1.0000x reference)
//
#include <hip/hip_runtime.h>
#include <hip/hip_bf16.h>

// ---------------- constants ----------------
#define Bb    8
#define Hp    14
#define Np    196      // tokens per image
#define EMB   512
#define RPEL  729
#define DEPTH 24
#define EPS   1e-5f

constexpr int EPI_NONE = 0, EPI_BIAS = 1, EPI_BIAS_GELU = 2, EPI_BIAS_RES = 3, EPI_ATOMIC = 4;

typedef __bf16 bf16x8 __attribute__((ext_vector_type(8)));
typedef __bf16 bf16x4 __attribute__((ext_vector_type(4)));
typedef float  f32x4  __attribute__((ext_vector_type(4)));

// ================= conv 4x4/4 + patchify + per-pixel LN =================
__global__ __launch_bounds__(128) void conv_ln_kernel(
    const float* __restrict__ img, const float* __restrict__ cw,
    const float* __restrict__ cb,  const float* __restrict__ png,
    const float* __restrict__ pnb, float* __restrict__ xout)
{
    int p = blockIdx.x;                 // b*3136 + h'*56 + w'
    int b = p / 3136, rem = p % 3136;
    int hh = rem / 56, ww = rem % 56;
    __shared__ float win[48];
    __shared__ float red[4];
    int t = threadIdx.x;
    if (t < 48) {
        int ic = t >> 4, kh = (t >> 2) & 3, kw = t & 3;
        win[t] = img[(((size_t)b*3 + ic)*224 + hh*4 + kh)*224 + ww*4 + kw];
    }
    __syncthreads();
    float acc = cb[t];
    const float* wrow = cw + (size_t)t * 48;
    #pragma unroll
    for (int r = 0; r < 48; ++r) acc += win[r] * wrow[r];
    float s = acc, ss = acc * acc;
    #pragma unroll
    for (int o = 32; o > 0; o >>= 1) { s += __shfl_xor(s, o, 64); ss += __shfl_xor(ss, o, 64); }
    int wv = t >> 6;
    if ((t & 63) == 0) { red[wv*2] = s; red[wv*2+1] = ss; }
    __syncthreads();
    s = red[0] + red[2]; ss = red[1] + red[3];
    float mean = s * (1.f/128.f);
    float rstd = rsqrtf(ss * (1.f/128.f) - mean*mean + EPS);
    float v = (acc - mean) * rstd * png[t] + pnb[t];
    int hp = hh >> 2, ih = hh & 3, wp = ww >> 2, iw = ww & 3;
    int bn = b * Np + hp * Hp + wp;
    xout[((size_t)bn*16 + ih*4 + iw)*128 + t] = v;
}

// ================= generic LayerNorm: one wave per row, f32 in -> bf16 out =================
__global__ __launch_bounds__(256) void ln_kernel(
    const float* __restrict__ x, const float* __restrict__ g,
    const float* __restrict__ b, __bf16* __restrict__ y, int M, int D)
{
    int wave = threadIdx.x >> 6, lane = threadIdx.x & 63;
    int row = blockIdx.x * 4 + wave;
    if (row >= M) return;
    const float* xr = x + (size_t)row * D;
    float s = 0.f, ss = 0.f;
    for (int i = lane; i < D; i += 64) { float v = xr[i]; s += v; ss += v*v; }
    #pragma unroll
    for (int o = 32; o > 0; o >>= 1) { s += __shfl_xor(s, o, 64); ss += __shfl_xor(ss, o, 64); }
    float inv = 1.f / (float)D;
    float mean = s * inv;
    float rstd = rsqrtf(ss * inv - mean*mean + EPS);
    __bf16* yr = y + (size_t)row * D;
    for (int i = lane; i < D; i += 64)
        yr[i] = (__bf16)((xr[i] - mean) * rstd * g[i] + b[i]);
}

// ================= merge1: gather 2x2 inner (dim128->512) + LN =================
__global__ __launch_bounds__(256) void merge1_ln_kernel(
    const float* __restrict__ x, const float* __restrict__ g,
    const float* __restrict__ b, __bf16* __restrict__ y)
{
    int wave = threadIdx.x >> 6, lane = threadIdx.x & 63;
    int row = blockIdx.x * 4 + wave;
    if (row >= 6272) return;
    int j2 = row & 1, i2 = (row >> 1) & 1, bn = row >> 2;
    float vals[8]; float s = 0.f, ss = 0.f;
    #pragma unroll
    for (int t = 0; t < 8; ++t) {
        int e = lane + t*64;
        int k = e >> 7, c = e & 127;
        int ih = 2*i2 + (k & 1), iw = 2*j2 + (k >> 1);
        float v = x[((size_t)bn*16 + ih*4 + iw)*128 + c];
        vals[t] = v; s += v; ss += v*v;
    }
    #pragma unroll
    for (int o = 32; o > 0; o >>= 1) { s += __shfl_xor(s, o, 64); ss += __shfl_xor(ss, o, 64); }
    float mean = s * (1.f/512.f);
    float rstd = rsqrtf(ss * (1.f/512.f) - mean*mean + EPS);
    __bf16* yr = y + (size_t)row * 512;
    #pragma unroll
    for (int t = 0; t < 8; ++t) {
        int e = lane + t*64;
        yr[e] = (__bf16)((vals[t] - mean) * rstd * g[e] + b[e]);
    }
}

// ================= merge2: gather 2x2 tokens (dim256->1024) + LN =================
__global__ __launch_bounds__(256) void merge2_ln_kernel(
    const float* __restrict__ x, const float* __restrict__ g,
    const float* __restrict__ b, __bf16* __restrict__ y)
{
    int wave = threadIdx.x >> 6, lane = threadIdx.x & 63;
    int row = blockIdx.x * 4 + wave;
    if (row >= 1568) return;
    float vals[16]; float s = 0.f, ss = 0.f;
    #pragma unroll
    for (int t = 0; t < 16; ++t) {
        int e = lane + t*64;
        int k = e >> 8, c = e & 255;
        float v = x[((size_t)row*4 + (k & 1)*2 + (k >> 1))*256 + c];
        vals[t] = v; s += v; ss += v*v;
    }
    #pragma unroll
    for (int o = 32; o > 0; o >>= 1) { s += __shfl_xor(s, o, 64); ss += __shfl_xor(ss, o, 64); }
    float mean = s * (1.f/1024.f);
    float rstd = rsqrtf(ss * (1.f/1024.f) - mean*mean + EPS);
    __bf16* yr = y + (size_t)row * 1024;
    #pragma unroll
    for (int t = 0; t < 16; ++t) {
        int e = lane + t*64;
        yr[e] = (__bf16)((vals[t] - mean) * rstd * g[e] + b[e]);
    }
}

// ================= weight transpose+cast: src[K][N] f32 -> dst[N][K] bf16 =================
// up to 4 matrices per launch; blockIdx.x = global 32x32 tile id, ranges via cum.
__global__ __launch_bounds__(256) void transpose4_kernel(
    const float* __restrict__ s0, const float* __restrict__ s1,
    const float* __restrict__ s2, const float* __restrict__ s3,
    __bf16* __restrict__ d0, __bf16* __restrict__ d1,
    __bf16* __restrict__ d2, __bf16* __restrict__ d3,
    int4 Kv, int4 Nv, int4 cum)
{
    __shared__ float tile[32][33];
    int t = blockIdx.x;
    int i   = (t < cum.x) ? 0 : (t < cum.y) ? 1 : (t < cum.z) ? 2 : 3;
    int base= (i == 0) ? 0 : (i == 1) ? cum.x : (i == 2) ? cum.y : cum.z;
    const float* src = (i == 0) ? s0 : (i == 1) ? s1 : (i == 2) ? s2 : s3;
    __bf16*      dst = (i == 0) ? d0 : (i == 1) ? d1 : (i == 2) ? d2 : d3;
    int K = (i == 0) ? Kv.x : (i == 1) ? Kv.y : (i == 2) ? Kv.z : Kv.w;
    int N = (i == 0) ? Nv.x : (i == 1) ? Nv.y : (i == 2) ? Nv.z : Nv.w;
    int lt = t - base;
    int ntx = N >> 5;
    int k0 = (lt / ntx) << 5, n0 = (lt % ntx) << 5;
    int tid = threadIdx.x;
    int c = tid & 31, r8 = tid >> 5;
    #pragma unroll
    for (int j = 0; j < 4; ++j) {
        int r = r8 + j*8;
        tile[r][c] = src[(size_t)(k0 + r) * N + n0 + c];
    }
    __syncthreads();
    int nr = tid >> 3, kc = (tid & 7) << 2;
    bf16x4 v;
    #pragma unroll
    for (int j = 0; j < 4; ++j) v[j] = (__bf16)tile[kc + j][nr];
    *(bf16x4*)&dst[(size_t)(n0 + nr) * K + k0 + kc] = v;
}

// ================= LDS-free MFMA GEMM: C[M,N] = epi(A[M,K] @ BT[N,K]^T) =================
// A bf16 [M,K] k-contig; BT bf16 [N,K] k-contig. Fragments straight from global.
// 64x64 block tile, 4 waves of 32x32. No LDS, no barriers.
// EPI_ATOMIC: split-K over blockIdx.z (chunk kChunk), atomicAdd onto f32 Cv
// (pre-initialized with residual/zeros); bias added by z==0 only.
template<int EPI>
__global__ __launch_bounds__(256) void gemm_tn_kernel(
    const __bf16* __restrict__ A, const __bf16* __restrict__ BT,
    const float* __restrict__ bias, const float* __restrict__ Rres,
    void* __restrict__ Cv, int M, int N, int K, int kChunk)
{
    const int tid  = threadIdx.x;
    const int lane = tid & 63, wave = tid >> 6;
    const int m0 = blockIdx.y << 6, n0 = blockIdx.x << 6;
    const int wm = (wave >> 1) << 5, wn = (wave & 1) << 5;
    const int q  = lane >> 4, mr = lane & 15;
    const int kstart = blockIdx.z * kChunk;
    const int kend   = min(kstart + kChunk, K);

    const int am0 = min(m0 + wm + mr,      M - 1);
    const int am1 = min(m0 + wm + 16 + mr, M - 1);
    const __bf16* a0 = A  + (size_t)am0 * K + q*8;
    const __bf16* a1 = A  + (size_t)am1 * K + q*8;
    const __bf16* b0 = BT + (size_t)(n0 + wn + mr)      * K + q*8;
    const __bf16* b1 = BT + (size_t)(n0 + wn + 16 + mr) * K + q*8;

    f32x4 acc[2][2];
    #pragma unroll
    for (int i = 0; i < 2; ++i)
        #pragma unroll
        for (int j = 0; j < 2; ++j)
            acc[i][j] = (f32x4){0.f, 0.f, 0.f, 0.f};

    #pragma unroll 4
    for (int k0 = kstart; k0 < kend; k0 += 32) {
        bf16x8 af0 = *(const bf16x8*)(a0 + k0);
        bf16x8 af1 = *(const bf16x8*)(a1 + k0);
        bf16x8 bf0 = *(const bf16x8*)(b0 + k0);
        bf16x8 bf1 = *(const bf16x8*)(b1 + k0);
        acc[0][0] = __builtin_amdgcn_mfma_f32_16x16x32_bf16(af0, bf0, acc[0][0], 0, 0, 0);
        acc[0][1] = __builtin_amdgcn_mfma_f32_16x16x32_bf16(af0, bf1, acc[0][1], 0, 0, 0);
        acc[1][0] = __builtin_amdgcn_mfma_f32_16x16x32_bf16(af1, bf0, acc[1][0], 0, 0, 0);
        acc[1][1] = __builtin_amdgcn_mfma_f32_16x16x32_bf16(af1, bf1, acc[1][1], 0, 0, 0);
    }

    const bool addb = (blockIdx.z == 0);
    #pragma unroll
    for (int si = 0; si < 2; ++si) {
        #pragma unroll
        for (int sj = 0; sj < 2; ++sj) {
            int n = n0 + wn + sj*16 + mr;
            float bv = 0.f;
            if constexpr (EPI != EPI_NONE) bv = bias[n];
            #pragma unroll
            for (int r = 0; r < 4; ++r) {
                int m = m0 + wm + si*16 + q*4 + r;
                if (m < M) {
                    if constexpr (EPI == EPI_ATOMIC) {
                        float v = acc[si][sj][r] + (addb ? bv : 0.f);
                        atomicAdd(&((float*)Cv)[(size_t)m * N + n], v);
                    } else {
                        float v = acc[si][sj][r] + bv;
                        if constexpr (EPI == EPI_BIAS_GELU)
                            v = 0.5f * v * (1.f + erff(v * 0.70710678118654752f));
                        if constexpr (EPI == EPI_BIAS_RES)
                            v += Rres[(size_t)m * N + n];
                        if constexpr (EPI == EPI_BIAS || EPI == EPI_BIAS_GELU)
                            ((__bf16*)Cv)[(size_t)m * N + n] = (__bf16)v;
                        else
                            ((float*)Cv)[(size_t)m * N + n] = v;
                    }
                }
            }
        }
    }
}

// ================= MFMA fused attention (bf16 qkv, bias pre-added) =================
__global__ __launch_bounds__(256) void attn_kernel(
    const __bf16* __restrict__ qkv, const float* __restrict__ tab,
    const int* __restrict__ rpe, __bf16* __restrict__ y2)
{
    __shared__ __bf16 Vt[64][232];        // V^T: [d][key]
    __shared__ __bf16 Pl[4][16][232];     // per-wave P tile [qrow][key]
    int blk = blockIdx.x;                 // b*32 + h*4 + qg
    int qg = blk & 3, h = (blk >> 2) & 7, b = blk >> 5;
    int tid = threadIdx.x;

    for (int i = tid; i < 196*8; i += 256) {
        int key = i >> 3, seg = i & 7;
        bf16x8 v = *(const bf16x8*)(qkv + ((size_t)(b*Np + key))*1536 + 1024 + h*64 + seg*8);
        #pragma unroll
        for (int j = 0; j < 8; ++j) Vt[seg*8 + j][key] = v[j];
    }
    {
        int d0 = tid >> 2, cs = tid & 3;
        #pragma unroll
        for (int j = 0; j < 9; ++j) Vt[d0][196 + cs*9 + j] = (__bf16)0.f;
    }
    __syncthreads();

    int lane = tid & 63, wave = tid >> 6;
    int T = qg + 4*wave;
    if (T > 12) return;
    int q = lane >> 4, mr = lane & 15;

    if (lane < 36) {
        #pragma unroll
        for (int r = 0; r < 16; ++r) Pl[wave][r][196 + lane] = (__bf16)0.f;
    }

    int qtok = b*Np + min(T*16 + mr, 195);
    const __bf16* qp = qkv + (size_t)qtok*1536 + h*64 + q*8;
    bf16x8 aq0 = *(const bf16x8*)qp;
    bf16x8 aq1 = *(const bf16x8*)(qp + 32);

    f32x4 sacc[13];
    #pragma unroll
    for (int nt = 0; nt < 13; ++nt) {
        int ktok = b*Np + min(nt*16 + mr, 195);
        const __bf16* kp = qkv + (size_t)ktok*1536 + 512 + h*64 + q*8;
        bf16x8 bk0 = *(const bf16x8*)kp;
        bf16x8 bk1 = *(const bf16x8*)(kp + 32);
        f32x4 z = (f32x4){0.f, 0.f, 0.f, 0.f};
        z = __builtin_amdgcn_mfma_f32_16x16x32_bf16(aq0, bk0, z, 0, 0, 0);
        sacc[nt] = __builtin_amdgcn_mfma_f32_16x16x32_bf16(aq1, bk1, z, 0, 0, 0);
    }

    #pragma unroll
    for (int r = 0; r < 4; ++r) {
        int qi = T*16 + q*4 + r;
        const int* rrow = rpe + (size_t)min(qi, 195) * 196;
        float vals[13];
        #pragma unroll
        for (int nt = 0; nt < 13; ++nt) {
            int col = nt*16 + mr;
            float bv = tab[rrow[min(col, 195)]*8 + h];
            float v = sacc[nt][r] * 0.125f + bv;
            vals[nt] = (col < 196) ? v : -3.0e38f;
        }
        float m = vals[0];
        #pragma unroll
        for (int nt = 1; nt < 13; ++nt) m = fmaxf(m, vals[nt]);
        #pragma unroll
        for (int o = 8; o > 0; o >>= 1) m = fmaxf(m, __shfl_xor(m, o, 64));
        float s = 0.f, p[13];
        #pragma unroll
        for (int nt = 0; nt < 13; ++nt) { p[nt] = __expf(vals[nt] - m); s += p[nt]; }
        #pragma unroll
        for (int o = 8; o > 0; o >>= 1) s += __shfl_xor(s, o, 64);
        float inv = 1.f / s;
        #pragma unroll
        for (int nt = 0; nt < 13; ++nt)
            Pl[wave][q*4 + r][nt*16 + mr] = (__bf16)(p[nt] * inv);
    }

    f32x4 oacc[4];
    #pragma unroll
    for (int nt = 0; nt < 4; ++nt) oacc[nt] = (f32x4){0.f, 0.f, 0.f, 0.f};
    #pragma unroll
    for (int ks = 0; ks < 7; ++ks) {
        bf16x8 ap = *(const bf16x8*)&Pl[wave][mr][ks*32 + q*8];
        #pragma unroll
        for (int nt = 0; nt < 4; ++nt) {
            bf16x8 bv = *(const bf16x8*)&Vt[nt*16 + mr][ks*32 + q*8];
            oacc[nt] = __builtin_amdgcn_mfma_f32_16x16x32_bf16(ap, bv, oacc[nt], 0, 0, 0);
        }
    }

    #pragma unroll
    for (int nt = 0; nt < 4; ++nt) {
        #pragma unroll
        for (int r = 0; r < 4; ++r) {
            int qi = T*16 + q*4 + r;
            if (qi < 196)
                y2[((size_t)(b*Np + qi))*512 + h*64 + nt*16 + mr] = (__bf16)oacc[nt][r];
        }
    }
}

// ================= ape add =================
__global__ __launch_bounds__(256) void add_ape_kernel(float* __restrict__ x,
                                                      const float* __restrict__ ape)
{
    int i = blockIdx.x * 256 + threadIdx.x;
    if (i < 1568*512) x[i] += ape[i % (Np*512)];
}

// ================= launcher =================
extern "C" void kernel_launch(void* const* d_in, const int* in_sizes, int n_in,
                              void* d_out, int out_size, void* d_ws, size_t ws_size,
                              hipStream_t stream)
{
    typedef const float* fp;
    fp image  = (fp)d_in[0];
    fp conv_w = (fp)d_in[1];  fp conv_b = (fp)d_in[2];
    fp pn_g   = (fp)d_in[3];  fp pn_b   = (fp)d_in[4];
    fp s1_ng  = (fp)d_in[5];  fp s1_nb  = (fp)d_in[6];
    fp s1_w1  = (fp)d_in[7];  fp s1_b1  = (fp)d_in[8];
    fp s1_w2  = (fp)d_in[9];  fp s1_b2  = (fp)d_in[10];
    fp s2_ng  = (fp)d_in[11]; fp s2_nb  = (fp)d_in[12];
    fp s2_w1  = (fp)d_in[13]; fp s2_b1  = (fp)d_in[14];
    fp s2_w2  = (fp)d_in[15]; fp s2_b2  = (fp)d_in[16];
    fp pm1_ng = (fp)d_in[17]; fp pm1_nb = (fp)d_in[18]; fp pm1_rw = (fp)d_in[19];
    fp pm2_ng = (fp)d_in[20]; fp pm2_nb = (fp)d_in[21]; fp pm2_rw = (fp)d_in[22];
    fp ape    = (fp)d_in[23];
    fp n1g    = (fp)d_in[24]; fp n1b    = (fp)d_in[25];
    fp qkvw   = (fp)d_in[26]; fp qkvb   = (fp)d_in[27];
    fp tab    = (fp)d_in[28];
    fp projw  = (fp)d_in[29]; fp projb  = (fp)d_in[30];
    fp n2g    = (fp)d_in[31]; fp n2b    = (fp)d_in[32];
    fp w1     = (fp)d_in[33]; fp b1     = (fp)d_in[34];
    fp w2     = (fp)d_in[35]; fp b2     = (fp)d_in[36];
    const int* rpe = (const int*)d_in[37];

    float*  X  = (float*)d_ws;                 // 3,211,264 f32 residual (12.8 MB)
    __bf16* W0 = (__bf16*)(X + 3211264);
    __bf16* Y  = W0;                           // 3,211,264  LN out / attn out
    __bf16* H  = W0 + 3211264;                 // 9,633,792  hidden / qkv
    __bf16* WT = W0 + 12845056;                // 3,145,728  per-layer transformer B^T
    __bf16* ST = W0 + 15990784;                // 2,129,920  stage B^T
    // stage BT offsets (elems, relative to ST)
    __bf16* s1w1T = ST;                        // 3 x [384,128]  (49152 each)
    __bf16* s1w2T = ST + 147456;               // 3 x [128,384]
    __bf16* s2w1T = ST + 294912;               // 3 x [768,256]  (196608 each)
    __bf16* s2w2T = ST + 884736;               // 3 x [256,768]
    __bf16* pm1T  = ST + 1474560;              // [256,512]
    __bf16* pm2T  = ST + 1605632;              // [512,1024]

    // ---- stage-weight transposes (4 launches) ----
    transpose4_kernel<<<192, 256, 0, stream>>>(
        s1_w1, s1_w1 + 49152, s1_w1 + 98304, s1_w2,
        s1w1T, s1w1T + 49152, s1w1T + 98304, s1w2T,
        make_int4(128,128,128,384), make_int4(384,384,384,128), make_int4(48,96,144,192));
    transpose4_kernel<<<480, 256, 0, stream>>>(
        s1_w2 + 49152, s1_w2 + 98304, s2_w1, s2_w1 + 196608,
        s1w2T + 49152, s1w2T + 98304, s2w1T, s2w1T + 196608,
        make_int4(384,384,256,256), make_int4(128,128,768,768), make_int4(48,96,288,480));
    transpose4_kernel<<<768, 256, 0, stream>>>(
        s2_w1 + 393216, s2_w2, s2_w2 + 196608, s2_w2 + 393216,
        s2w1T + 393216, s2w2T, s2w2T + 196608, s2w2T + 393216,
        make_int4(256,768,768,768), make_int4(768,256,256,256), make_int4(192,384,576,768));
    transpose4_kernel<<<640, 256, 0, stream>>>(
        pm1_rw, pm2_rw, pm2_rw, pm2_rw,
        pm1T, pm2T, pm2T, pm2T,
        make_int4(512,1024,0,0), make_int4(256,512,0,0), make_int4(128,640,640,640));

    conv_ln_kernel<<<Bb*56*56, 128, 0, stream>>>(image, conv_w, conv_b, pn_g, pn_b, X);

    for (int t = 0; t < 3; ++t) {
        ln_kernel<<<25088/4, 256, 0, stream>>>(X, s1_ng + t*128, s1_nb + t*128, Y, 25088, 128);
        gemm_tn_kernel<EPI_BIAS_GELU><<<dim3(384/64, 25088/64), 256, 0, stream>>>(
            Y, s1w1T + t*49152, s1_b1 + t*384, nullptr, H, 25088, 384, 128, 128);
        gemm_tn_kernel<EPI_BIAS_RES><<<dim3(128/64, 25088/64), 256, 0, stream>>>(
            H, s1w2T + t*49152, s1_b2 + t*128, X, X, 25088, 128, 384, 384);
    }
    merge1_ln_kernel<<<6272/4, 256, 0, stream>>>(X, pm1_ng, pm1_nb, Y);
    gemm_tn_kernel<EPI_NONE><<<dim3(256/64, 6272/64), 256, 0, stream>>>(
        Y, pm1T, nullptr, nullptr, X, 6272, 256, 512, 512);
    for (int t = 0; t < 3; ++t) {
        ln_kernel<<<6272/4, 256, 0, stream>>>(X, s2_ng + t*256, s2_nb + t*256, Y, 6272, 256);
        gemm_tn_kernel<EPI_BIAS_GELU><<<dim3(768/64, 6272/64), 256, 0, stream>>>(
            Y, s2w1T + t*196608, s2_b1 + t*768, nullptr, H, 6272, 768, 256, 256);
        gemm_tn_kernel<EPI_BIAS_RES><<<dim3(256/64, 6272/64), 256, 0, stream>>>(
            H, s2w2T + t*196608, s2_b2 + t*256, X, X, 6272, 256, 768, 768);
    }
    merge2_ln_kernel<<<1568/4, 256, 0, stream>>>(X, pm2_ng, pm2_nb, Y);
    gemm_tn_kernel<EPI_NONE><<<dim3(512/64, (1568+63)/64), 256, 0, stream>>>(
        Y, pm2T, nullptr, nullptr, X, 1568, 512, 1024, 1024);
    add_ape_kernel<<<(1568*512+255)/256, 256, 0, stream>>>(X, ape);

    const int MT = (1568 + 63) / 64;   // 25
    for (int l = 0; l < DEPTH; ++l) {
        // per-layer weight transpose: qkv | proj | w1 | w2  -> WT
        transpose4_kernel<<<3072, 256, 0, stream>>>(
            qkvw + (size_t)l*512*1536, projw + (size_t)l*512*512,
            w1   + (size_t)l*512*2048, w2    + (size_t)l*2048*512,
            WT, WT + 786432, WT + 1048576, WT + 2097152,
            make_int4(512,512,512,2048), make_int4(1536,512,2048,512),
            make_int4(768,1024,2048,3072));
        ln_kernel<<<392, 256, 0, stream>>>(X, n1g + l*EMB, n1b + l*EMB, Y, 1568, EMB);
        gemm_tn_kernel<EPI_BIAS><<<dim3(1536/64, MT), 256, 0, stream>>>(
            Y, WT, qkvb + (size_t)l*1536, nullptr, H, 1568, 1536, EMB, EMB);
        attn_kernel<<<256, 256, 0, stream>>>(H, tab + (size_t)l*RPEL*8, rpe, Y);
        gemm_tn_kernel<EPI_ATOMIC><<<dim3(512/64, MT, 4), 256, 0, stream>>>(
            Y, WT + 786432, projb + (size_t)l*EMB, nullptr, X, 1568, EMB, EMB, 128);
        ln_kernel<<<392, 256, 0, stream>>>(X, n2g + l*EMB, n2b + l*EMB, Y, 1568, EMB);
        gemm_tn_kernel<EPI_BIAS_GELU><<<dim3(2048/64, MT), 256, 0, stream>>>(
            Y, WT + 1048576, b1 + (size_t)l*2048, nullptr, H, 1568, 2048, EMB, EMB);
        gemm_tn_kernel<EPI_ATOMIC><<<dim3(512/64, MT, 4), 256, 0, stream>>>(
            H, WT + 2097152, b2 + (size_t)l*EMB, nullptr, X, 1568, EMB, 2048, 512);
    }
    hipMemcpyAsync(d_out, X, (size_t)1568*512*sizeof(float), hipMemcpyDeviceToDevice, stream);
}